// Round 1
// baseline (499.336 us; speedup 1.0000x reference)
//
#include <hip/hip_runtime.h>

#define BATCH 16
#define N_RIGIDS 8192
#define N_RES 2048
#define C_FRAME 384
#define C_S 384
#define N_AA 21
#define N_AA_PAD 24
#define EPS 1e-5f

#define N_RIG_TOT (BATCH * N_RIGIDS)   // 131072
#define N_ROWS    (BATCH * N_RES)      // 32768
#define CAP 32                         // max rigids per residue (lambda=4; P(>=32)~1e-14)
#define ZROW 32                        // floats per bucket slot row (128 B aligned)

// ws layout (float-offset units; ints aliased where noted)
#define GC_OFF 0                               // [8064] Gc = ln_g * (W_su@W_out)
#define CS_OFF 8192                            // [21]   colsum(Gc)        (atomic-accumulated, pre-zeroed)
#define B2_OFF 8256                            // [21]   ln_b@Wc + b_su@W_out (atomic-accumulated, pre-zeroed)
#define WP_OFF 8320                            // [384*24] W_out padded to 24 cols (16B-aligned rows)
#define HIST_OFF 18432                         // int[32768]
#define ZB_OFF 65536                           // [32768*32*32] bucket-ordered contributions (134 MB)

// ---- k0: fused precompute, parallel over (f-block, a). grid (6, 22) x 64 threads.
// blockIdx.y == 21 writes the padded W_out copy; else Gc[f,a] + atomic colsum/bias2.
__global__ void __launch_bounds__(64) precompute_fused(const float* __restrict__ W_su,
                                                       const float* __restrict__ W_out,
                                                       const float* __restrict__ ln_g,
                                                       const float* __restrict__ ln_b,
                                                       const float* __restrict__ b_su,
                                                       float* __restrict__ ws) {
    const int f = blockIdx.x * 64 + threadIdx.x;
    if (blockIdx.y == N_AA) {
        // pad-copy W_out[384][21] -> Wp[384][24] (rows 96 B -> float4-aligned)
        float* wp = ws + WP_OFF + (size_t)f * N_AA_PAD;
        const float* wo = W_out + (size_t)f * N_AA;
#pragma unroll
        for (int a = 0; a < N_AA; ++a) wp[a] = wo[a];
        wp[21] = 0.f; wp[22] = 0.f; wp[23] = 0.f;
        return;
    }
    const int a = blockIdx.y;
    const float4* wrow = (const float4*)(W_su + (size_t)f * C_S);
    float wc = 0.f;
    for (int j = 0; j < C_S / 4; ++j) {
        float4 v = wrow[j];
        // W_out accesses are wave-uniform (a uniform, j uniform) -> scalar loads
        wc += v.x * W_out[(4 * j + 0) * N_AA + a];
        wc += v.y * W_out[(4 * j + 1) * N_AA + a];
        wc += v.z * W_out[(4 * j + 2) * N_AA + a];
        wc += v.w * W_out[(4 * j + 3) * N_AA + a];
    }
    float gval = ln_g[f] * wc;
    ws[GC_OFF + f * N_AA + a] = gval;
    float bval = ln_b[f] * wc + b_su[f] * W_out[f * N_AA + a];
    float g = gval, b = bval;
#pragma unroll
    for (int off = 32; off >= 1; off >>= 1) {
        g += __shfl_xor(g, off);
        b += __shfl_xor(b, off);
    }
    if (threadIdx.x == 0) {
        atomicAdd(ws + CS_OFF + a, g);
        atomicAdd(ws + B2_OFF + a, b);
    }
}

// ---- k1: double-buffered LDS-staged LN + skinny proj -> bucket slot write ----
// 128 threads / 128 rigids per block; 12 chunks of 32 channels. (UNCHANGED this round)
__global__ void __launch_bounds__(128) zcompute(const float* __restrict__ embed,
                                                const int* __restrict__ idx,
                                                const float* __restrict__ mask,
                                                const float* __restrict__ ws,
                                                float* __restrict__ zb,
                                                int* __restrict__ hist) {
    __shared__ float lds[2][128 * 33];
    const int tid = threadIdx.x;
    const int t = blockIdx.x * 128 + tid;
    const float* __restrict__ Gc = ws + GC_OFF;
    const float4* gb = (const float4*)(embed + (size_t)blockIdx.x * (128 * C_FRAME));
    float4 buf[8];
    float d[N_AA];
#pragma unroll
    for (int a = 0; a < N_AA; ++a) d[a] = 0.f;
    float sum = 0.f, sumsq = 0.f;

    // preload chunk 0
#pragma unroll
    for (int k = 0; k < 8; ++k) {
        int f4 = tid + 128 * k;
        buf[k] = gb[(f4 >> 3) * 96 + (f4 & 7)];
    }
#pragma unroll
    for (int k = 0; k < 8; ++k) {
        int f4 = tid + 128 * k;
        float* p = &lds[0][(f4 >> 3) * 33 + (f4 & 7) * 4];
        p[0] = buf[k].x; p[1] = buf[k].y; p[2] = buf[k].z; p[3] = buf[k].w;
    }
    __syncthreads();

    for (int c = 0; c < 12; ++c) {
        if (c + 1 < 12) {
            const float4* gn = gb + (c + 1) * 8;
#pragma unroll
            for (int k = 0; k < 8; ++k) {
                int f4 = tid + 128 * k;
                buf[k] = gn[(f4 >> 3) * 96 + (f4 & 7)];
            }
        }
        const float* row = &lds[c & 1][tid * 33];
        const float* g = Gc + (c * 32) * N_AA;     // wave-uniform -> scalar loads
#pragma unroll 4
        for (int cc = 0; cc < 32; ++cc) {
            float x = row[cc];
            sum += x; sumsq += x * x;
#pragma unroll
            for (int a = 0; a < N_AA; ++a) d[a] += x * g[cc * N_AA + a];
        }
        if (c + 1 < 12) {
#pragma unroll
            for (int k = 0; k < 8; ++k) {
                int f4 = tid + 128 * k;
                float* p = &lds[(c + 1) & 1][(f4 >> 3) * 33 + (f4 & 7) * 4];
                p[0] = buf[k].x; p[1] = buf[k].y; p[2] = buf[k].z; p[3] = buf[k].w;
            }
            __syncthreads();
        }
    }

    float mu  = sum * (1.f / C_FRAME);
    float var = sumsq * (1.f / C_FRAME) - mu * mu;
    float inv = rsqrtf(var + EPS);
    float m = mask[t];
    int res = idx[t];
    int b = t >> 13;
    int g = (b << 11) + res;
    const float* cs = ws + CS_OFF;
    const float* b2 = ws + B2_OFF;
    float v[N_AA];
#pragma unroll
    for (int a = 0; a < N_AA; ++a) v[a] = m * (inv * (d[a] - mu * cs[a]) + b2[a]);
    int slot = atomicAdd(hist + g, 1);
    if (slot < CAP) {
        float4* zr = (float4*)(zb + ((size_t)g * CAP + slot) * ZROW);
        zr[0] = make_float4(v[0], v[1], v[2], v[3]);
        zr[1] = make_float4(v[4], v[5], v[6], v[7]);
        zr[2] = make_float4(v[8], v[9], v[10], v[11]);
        zr[3] = make_float4(v[12], v[13], v[14], v[15]);
        zr[4] = make_float4(v[16], v[17], v[18], v[19]);
        ((float*)zr)[20] = v[20];
    }
}

// ---- k2: base projection, K-split-4 for occupancy ----
// 1024 blocks x 128 threads; 32 rows/block, 4 lanes per row (96 K-cols each)
// -> 8 waves/CU (was 2). Weight loads via padded Wp as float4 (L1-resident).
__global__ void __launch_bounds__(128) final_gather(const float* __restrict__ out_in,
                                                    const float* __restrict__ b_out,
                                                    const float* __restrict__ ws,
                                                    const float* __restrict__ zb,
                                                    const int* __restrict__ hist,
                                                    float* __restrict__ logits) {
    __shared__ float lds[2][32 * 33];
    const int tid = threadIdx.x;
    const int r = tid >> 2;            // row within block (0..31)
    const int ks = tid & 3;            // K-split lane (0..3)
    const int gidx = blockIdx.x * 32 + r;
    const float* __restrict__ Wp = ws + WP_OFF;
    const float4* gb = (const float4*)(out_in + (size_t)blockIdx.x * (32 * C_S));
    float4 buf[2];
    float acc[N_AA_PAD];
#pragma unroll
    for (int a = 0; a < N_AA_PAD; ++a) acc[a] = 0.f;

    // preload chunk 0: 32 rows x 32 cols = 256 float4, 2 per thread
#pragma unroll
    for (int k = 0; k < 2; ++k) {
        int f4 = tid + 128 * k;
        buf[k] = gb[(f4 >> 3) * 96 + (f4 & 7)];
    }
#pragma unroll
    for (int k = 0; k < 2; ++k) {
        int f4 = tid + 128 * k;
        float* p = &lds[0][(f4 >> 3) * 33 + (f4 & 7) * 4];
        p[0] = buf[k].x; p[1] = buf[k].y; p[2] = buf[k].z; p[3] = buf[k].w;
    }
    __syncthreads();

    for (int c = 0; c < 12; ++c) {
        if (c + 1 < 12) {
            const float4* gn = gb + (c + 1) * 8;
#pragma unroll
            for (int k = 0; k < 2; ++k) {
                int f4 = tid + 128 * k;
                buf[k] = gn[(f4 >> 3) * 96 + (f4 & 7)];
            }
        }
        // lane ks consumes cols [c*32 + ks*8, +8); bank = (r + 8*ks + cc) % 32 -> 2-way max (free)
        const float* row = &lds[c & 1][r * 33 + ks * 8];
        const float4* w4 = (const float4*)(Wp + (size_t)(c * 32 + ks * 8) * N_AA_PAD);
#pragma unroll
        for (int cc = 0; cc < 8; ++cc) {
            float x = row[cc];
#pragma unroll
            for (int q = 0; q < 6; ++q) {
                float4 wv = w4[cc * 6 + q];
                acc[4 * q + 0] += x * wv.x;
                acc[4 * q + 1] += x * wv.y;
                acc[4 * q + 2] += x * wv.z;
                acc[4 * q + 3] += x * wv.w;
            }
        }
        if (c + 1 < 12) {
#pragma unroll
            for (int k = 0; k < 2; ++k) {
                int f4 = tid + 128 * k;
                float* p = &lds[(c + 1) & 1][(f4 >> 3) * 33 + (f4 & 7) * 4];
                p[0] = buf[k].x; p[1] = buf[k].y; p[2] = buf[k].z; p[3] = buf[k].w;
            }
            __syncthreads();
        }
    }

    // epilogue: bucket sum split across the 4 K-lanes (slot i % 4 == ks),
    // fused with the K-split butterfly reduction. All register indices compile-time.
    int cnt = hist[gidx];
    if (cnt > CAP) cnt = CAP;
    const float* zbase = zb + (size_t)gidx * CAP * ZROW;
    float* o = logits + (size_t)gidx * N_AA;
#pragma unroll
    for (int a = 0; a < N_AA; ++a) {
        float t = acc[a];
        if (ks == 0) t += b_out[a];
        for (int i = ks; i < cnt; i += 4) t += zbase[i * ZROW + a];
        t += __shfl_xor(t, 1);
        t += __shfl_xor(t, 2);
        if (ks == 0) o[a] = t;
    }
}

extern "C" void kernel_launch(void* const* d_in, const int* in_sizes, int n_in,
                              void* d_out, int out_size, void* d_ws, size_t ws_size,
                              hipStream_t stream) {
    const float* embed  = (const float*)d_in[0];
    const int*   idx    = (const int*)d_in[1];
    const float* mask   = (const float*)d_in[2];
    const float* out_in = (const float*)d_in[3];
    const float* ln_g   = (const float*)d_in[4];
    const float* ln_b   = (const float*)d_in[5];
    const float* W_su   = (const float*)d_in[6];
    const float* b_su   = (const float*)d_in[7];
    const float* W_out  = (const float*)d_in[8];
    const float* b_out  = (const float*)d_in[9];
    float* logits = (float*)d_out;
    float* ws = (float*)d_ws;
    float* zb   = ws + ZB_OFF;
    int*   hist = (int*)(ws + HIST_OFF);

    hipMemsetAsync(hist, 0, N_ROWS * sizeof(int), stream);
    hipMemsetAsync(ws + CS_OFF, 0, (B2_OFF - CS_OFF + N_AA) * sizeof(float), stream);
    hipLaunchKernelGGL(precompute_fused, dim3(6, N_AA + 1), dim3(64), 0, stream,
                       W_su, W_out, ln_g, ln_b, b_su, ws);
    hipLaunchKernelGGL(zcompute, dim3(N_RIG_TOT / 128), dim3(128), 0, stream,
                       embed, idx, mask, ws, zb, hist);
    hipLaunchKernelGGL(final_gather, dim3(N_ROWS / 32), dim3(128), 0, stream,
                       out_in, b_out, ws, zb, hist, logits);
}

// Round 3
// 430.443 us; speedup vs baseline: 1.1601x; 1.1601x over previous
//
#include <hip/hip_runtime.h>

#define BATCH 16
#define N_RIGIDS 8192
#define N_RES 2048
#define C_FRAME 384
#define C_S 384
#define N_AA 21
#define EPS 1e-5f

#define N_RIG_TOT (BATCH * N_RIGIDS)   // 131072
#define N_ROWS    (BATCH * N_RES)      // 32768
#define CAP 32                         // max rigids per residue (lambda=4; P(>=32)~1e-14)
#define ZROW 32                        // floats per bucket slot row (128 B aligned)

// ws layout (float-offset units; ints aliased where noted)
#define GC_OFF 0                               // [8064] Gc = ln_g * (W_su@W_out)
#define CS_OFF 8192                            // [21]   colsum(Gc)        (atomic-accumulated, pre-zeroed)
#define B2_OFF 8256                            // [21]   ln_b@Wc + b_su@W_out (atomic-accumulated, pre-zeroed)
#define HIST_OFF 18432                         // int[32768]
#define ZB_OFF 65536                           // [32768*32*32] bucket-ordered contributions (134 MB)

// ---- k0: fused precompute, parallel over (f-block, a). grid (6, 21) x 64 threads.
__global__ void __launch_bounds__(64) precompute_fused(const float* __restrict__ W_su,
                                                       const float* __restrict__ W_out,
                                                       const float* __restrict__ ln_g,
                                                       const float* __restrict__ ln_b,
                                                       const float* __restrict__ b_su,
                                                       float* __restrict__ ws) {
    const int f = blockIdx.x * 64 + threadIdx.x;
    const int a = blockIdx.y;
    const float4* wrow = (const float4*)(W_su + (size_t)f * C_S);
    float wc = 0.f;
    for (int j = 0; j < C_S / 4; ++j) {
        float4 v = wrow[j];
        // W_out accesses are wave-uniform (a uniform, j uniform) -> scalar loads
        wc += v.x * W_out[(4 * j + 0) * N_AA + a];
        wc += v.y * W_out[(4 * j + 1) * N_AA + a];
        wc += v.z * W_out[(4 * j + 2) * N_AA + a];
        wc += v.w * W_out[(4 * j + 3) * N_AA + a];
    }
    float gval = ln_g[f] * wc;
    ws[GC_OFF + f * N_AA + a] = gval;
    float bval = ln_b[f] * wc + b_su[f] * W_out[f * N_AA + a];
    float g = gval, b = bval;
#pragma unroll
    for (int off = 32; off >= 1; off >>= 1) {
        g += __shfl_xor(g, off);
        b += __shfl_xor(b, off);
    }
    if (threadIdx.x == 0) {
        atomicAdd(ws + CS_OFF + a, g);
        atomicAdd(ws + B2_OFF + a, b);
    }
}

// ---- k1: double-buffered LDS-staged LN + skinny proj -> bucket slot write ----
// 128 threads / 128 rigids per block; 12 chunks of 32 channels. (UNCHANGED this round)
__global__ void __launch_bounds__(128) zcompute(const float* __restrict__ embed,
                                                const int* __restrict__ idx,
                                                const float* __restrict__ mask,
                                                const float* __restrict__ ws,
                                                float* __restrict__ zb,
                                                int* __restrict__ hist) {
    __shared__ float lds[2][128 * 33];
    const int tid = threadIdx.x;
    const int t = blockIdx.x * 128 + tid;
    const float* __restrict__ Gc = ws + GC_OFF;
    const float4* gb = (const float4*)(embed + (size_t)blockIdx.x * (128 * C_FRAME));
    float4 buf[8];
    float d[N_AA];
#pragma unroll
    for (int a = 0; a < N_AA; ++a) d[a] = 0.f;
    float sum = 0.f, sumsq = 0.f;

    // preload chunk 0
#pragma unroll
    for (int k = 0; k < 8; ++k) {
        int f4 = tid + 128 * k;
        buf[k] = gb[(f4 >> 3) * 96 + (f4 & 7)];
    }
#pragma unroll
    for (int k = 0; k < 8; ++k) {
        int f4 = tid + 128 * k;
        float* p = &lds[0][(f4 >> 3) * 33 + (f4 & 7) * 4];
        p[0] = buf[k].x; p[1] = buf[k].y; p[2] = buf[k].z; p[3] = buf[k].w;
    }
    __syncthreads();

    for (int c = 0; c < 12; ++c) {
        if (c + 1 < 12) {
            const float4* gn = gb + (c + 1) * 8;
#pragma unroll
            for (int k = 0; k < 8; ++k) {
                int f4 = tid + 128 * k;
                buf[k] = gn[(f4 >> 3) * 96 + (f4 & 7)];
            }
        }
        const float* row = &lds[c & 1][tid * 33];
        const float* g = Gc + (c * 32) * N_AA;     // wave-uniform -> scalar loads
#pragma unroll 4
        for (int cc = 0; cc < 32; ++cc) {
            float x = row[cc];
            sum += x; sumsq += x * x;
#pragma unroll
            for (int a = 0; a < N_AA; ++a) d[a] += x * g[cc * N_AA + a];
        }
        if (c + 1 < 12) {
#pragma unroll
            for (int k = 0; k < 8; ++k) {
                int f4 = tid + 128 * k;
                float* p = &lds[(c + 1) & 1][(f4 >> 3) * 33 + (f4 & 7) * 4];
                p[0] = buf[k].x; p[1] = buf[k].y; p[2] = buf[k].z; p[3] = buf[k].w;
            }
            __syncthreads();
        }
    }

    float mu  = sum * (1.f / C_FRAME);
    float var = sumsq * (1.f / C_FRAME) - mu * mu;
    float inv = rsqrtf(var + EPS);
    float m = mask[t];
    int res = idx[t];
    int b = t >> 13;
    int g = (b << 11) + res;
    const float* cs = ws + CS_OFF;
    const float* b2 = ws + B2_OFF;
    float v[N_AA];
#pragma unroll
    for (int a = 0; a < N_AA; ++a) v[a] = m * (inv * (d[a] - mu * cs[a]) + b2[a]);
    int slot = atomicAdd(hist + g, 1);
    if (slot < CAP) {
        float4* zr = (float4*)(zb + ((size_t)g * CAP + slot) * ZROW);
        zr[0] = make_float4(v[0], v[1], v[2], v[3]);
        zr[1] = make_float4(v[4], v[5], v[6], v[7]);
        zr[2] = make_float4(v[8], v[9], v[10], v[11]);
        zr[3] = make_float4(v[12], v[13], v[14], v[15]);
        zr[4] = make_float4(v[16], v[17], v[18], v[19]);
        ((float*)zr)[20] = v[20];
    }
}

// ---- k2: base projection, wave-level K-split ----
// 512 blocks x 256 threads (4 waves). Block owns 64 rows; wave w owns K-chunks
// {w, w+4, w+8} (96 cols). Weight addr uniform within wave -> scalar s_loads
// (round-1 lesson: per-lane weight loads flood VMEM). 2048 waves = 2 waves/SIMD
// (round-0 lesson: 0.5 waves/SIMD hides nothing).
// Round-2 lesson: static __shared__ caps at 64 KiB -> single per-wave LDS buffer
// (33.8 KB) + register prefetch instead of LDS double-buffer.
__global__ void __launch_bounds__(256) final_gather(const float* __restrict__ out_in,
                                                    const float* __restrict__ W_out,
                                                    const float* __restrict__ b_out,
                                                    const float* __restrict__ zb,
                                                    const int* __restrict__ hist,
                                                    float* __restrict__ logits) {
    __shared__ float lds[4][64 * 33];  // 33.8 KB: per-wave staging (single buffer)
    const int tid = threadIdx.x;
    const int w = tid >> 6;            // wave id (K-part)
    const int l = tid & 63;            // lane = row within block
    const float4* gb = (const float4*)(out_in + (size_t)blockIdx.x * (64 * C_S));
    float4 buf[8];
    float acc[N_AA];
#pragma unroll
    for (int a = 0; a < N_AA; ++a) acc[a] = 0.f;

    // preload chunk j=0 (c = w): 64 rows x 8 float4-cols, 8 per lane, coalesced
#pragma unroll
    for (int k = 0; k < 8; ++k) {
        int f4 = l + 64 * k;
        buf[k] = gb[(f4 >> 3) * 96 + w * 8 + (f4 & 7)];
    }
#pragma unroll
    for (int k = 0; k < 8; ++k) {
        int f4 = l + 64 * k;
        float* p = &lds[w][(f4 >> 3) * 33 + (f4 & 7) * 4];
        p[0] = buf[k].x; p[1] = buf[k].y; p[2] = buf[k].z; p[3] = buf[k].w;
    }
    __syncthreads();

    for (int j = 0; j < 3; ++j) {
        const int c = w + 4 * j;
        if (j < 2) {
            const int cn = c + 4;   // prefetch next chunk into registers
#pragma unroll
            for (int k = 0; k < 8; ++k) {
                int f4 = l + 64 * k;
                buf[k] = gb[(f4 >> 3) * 96 + cn * 8 + (f4 & 7)];
            }
        }
        const float* srow = &lds[w][l * 33];              // bank (l+cc)%32: 2-way, free
        const float* g = W_out + (size_t)(c * 32) * N_AA; // wave-uniform -> scalar loads
#pragma unroll 4
        for (int cc = 0; cc < 32; ++cc) {
            float x = srow[cc];
#pragma unroll
            for (int a = 0; a < N_AA; ++a) acc[a] += x * g[cc * N_AA + a];
        }
        if (j < 2) {
            __syncthreads();   // all reads of current chunk done before overwrite
#pragma unroll
            for (int k = 0; k < 8; ++k) {
                int f4 = l + 64 * k;
                float* p = &lds[w][(f4 >> 3) * 33 + (f4 & 7) * 4];
                p[0] = buf[k].x; p[1] = buf[k].y; p[2] = buf[k].z; p[3] = buf[k].w;
            }
            __syncthreads();   // writes visible before next compute
        }
    }

    // cross-wave reduction: alias staging LDS as red[4][64][22] (5632 floats,
    // fits in first 22.5 KB; all staging reads completed before this barrier)
    __syncthreads();
    float* red = (float*)lds;
    float* myred = red + ((size_t)w * 64 + l) * 22;
#pragma unroll
    for (int a = 0; a < N_AA; ++a) myred[a] = acc[a];
    __syncthreads();

    // epilogue: thread t -> row r = t>>2, aa-stripe j = t&3 (a = j, j+4, ...)
    // fused with bucket-slot sum (slots contiguous per row, 128 B aligned)
    const int r = tid >> 2;
    const int jj = tid & 3;
    const int gidx = blockIdx.x * 64 + r;
    int cnt = hist[gidx];
    if (cnt > CAP) cnt = CAP;
    const float* zbase = zb + (size_t)gidx * CAP * ZROW;
    float* o = logits + (size_t)gidx * N_AA;
    for (int a = jj; a < N_AA; a += 4) {
        float t4 = b_out[a]
                 + red[(0 * 64 + r) * 22 + a] + red[(1 * 64 + r) * 22 + a]
                 + red[(2 * 64 + r) * 22 + a] + red[(3 * 64 + r) * 22 + a];
        for (int i = 0; i < cnt; ++i) t4 += zbase[i * ZROW + a];
        o[a] = t4;
    }
}

extern "C" void kernel_launch(void* const* d_in, const int* in_sizes, int n_in,
                              void* d_out, int out_size, void* d_ws, size_t ws_size,
                              hipStream_t stream) {
    const float* embed  = (const float*)d_in[0];
    const int*   idx    = (const int*)d_in[1];
    const float* mask   = (const float*)d_in[2];
    const float* out_in = (const float*)d_in[3];
    const float* ln_g   = (const float*)d_in[4];
    const float* ln_b   = (const float*)d_in[5];
    const float* W_su   = (const float*)d_in[6];
    const float* b_su   = (const float*)d_in[7];
    const float* W_out  = (const float*)d_in[8];
    const float* b_out  = (const float*)d_in[9];
    float* logits = (float*)d_out;
    float* ws = (float*)d_ws;
    float* zb   = ws + ZB_OFF;
    int*   hist = (int*)(ws + HIST_OFF);

    hipMemsetAsync(hist, 0, N_ROWS * sizeof(int), stream);
    hipMemsetAsync(ws + CS_OFF, 0, (B2_OFF - CS_OFF + N_AA) * sizeof(float), stream);
    hipLaunchKernelGGL(precompute_fused, dim3(6, N_AA), dim3(64), 0, stream,
                       W_su, W_out, ln_g, ln_b, b_su, ws);
    hipLaunchKernelGGL(zcompute, dim3(N_RIG_TOT / 128), dim3(128), 0, stream,
                       embed, idx, mask, ws, zb, hist);
    hipLaunchKernelGGL(final_gather, dim3(N_ROWS / 64), dim3(256), 0, stream,
                       out_in, W_out, b_out, zb, hist, logits);
}